// Round 2
// baseline (796.904 us; speedup 1.0000x reference)
//
#include <hip/hip_runtime.h>
#include <stdint.h>

#define B_SZ 1024
#define F_SZ 104013
#define NFIELD 39
#define N_RAW 312
#define N_PAD 320
#define KB_STEPS 3251            // ceil(104013 / 32)
#define PART_ELEMS ((size_t)B_SZ * N_PAD)

using bf16x8 = __attribute__((ext_vector_type(8))) short;
using f32x4  = __attribute__((ext_vector_type(4))) float;
typedef float f4u __attribute__((vector_size(16), aligned(4)));  // unaligned-tolerant float4

__device__ __forceinline__ unsigned int pack_bf16(float a, float b) {
  // round-half-up to bf16, pack two into one dword (lo = a, hi = b)
  unsigned int ua = __float_as_uint(a) + 0x8000u;
  unsigned int ub = __float_as_uint(b) + 0x8000u;
  return (ua >> 16) | (ub & 0xffff0000u);
}

// ---------------------------------------------------------------------------
// Kernel 1: transpose+convert v (plus w as column 312, zero pad to 320) into
// MFMA B-fragment order: chunk index (kb*20+nt)*64 + lane holds 8 bf16 with
// B[k = kb*32 + (lane>>4)*8 + j][n = nt*16 + (lane&15)], 16B per lane.
// ---------------------------------------------------------------------------
__global__ __launch_bounds__(256) void pack_v(const float* __restrict__ v,
                                              const float* __restrict__ w,
                                              uint4* __restrict__ Bp) {
  const int kb = blockIdx.x;
  const int t  = threadIdx.x;
  __shared__ float vs[32][324];   // 324 stride: 16B-aligned rows + bank skew

  for (int idx = t; idx < 32 * 78; idx += 256) {
    int r = idx / 78, c4 = (idx % 78) * 4;
    int k = kb * 32 + r;
    float4 val = make_float4(0.f, 0.f, 0.f, 0.f);
    if (k < F_SZ) val = *(const float4*)(v + (size_t)k * N_RAW + c4);
    *(float4*)&vs[r][c4] = val;
  }
  if (t < 32) {
    int k = kb * 32 + t;
    vs[t][312] = (k < F_SZ) ? w[k] : 0.f;
#pragma unroll
    for (int c = 313; c < 320; ++c) vs[t][c] = 0.f;
  }
  __syncthreads();

#pragma unroll
  for (int i = 0; i < 5; ++i) {
    int p  = t + 256 * i;          // p = nt*64 + lane
    int l  = p & 63;
    int kr = (l >> 4) * 8;
    int col = (p >> 6) * 16 + (l & 15);
    uint4 o;
    o.x = pack_bf16(vs[kr + 0][col], vs[kr + 1][col]);
    o.y = pack_bf16(vs[kr + 2][col], vs[kr + 3][col]);
    o.z = pack_bf16(vs[kr + 4][col], vs[kr + 5][col]);
    o.w = pack_bf16(vs[kr + 6][col], vs[kr + 7][col]);
    Bp[(size_t)kb * 1280 + p] = o;
  }
}

// ---------------------------------------------------------------------------
// Kernel 2: LDS-free split-K MFMA GEMM, spill-proofed.
// Block: 4 waves over 128 rows x 320 cols; wave = 64 rows (4 bands of 16)
// x 160 cols (10 n-tiles of 16). Grid (8 M-tiles, S k-splits).
// VGPR budget: acc 160 + bv 40 + afrag 16 + araw 16 (2 bands staged at a
// time) + ptrs ~12 = ~246 < 256 -> 2 waves/SIMD guaranteed, no scratch.
// ---------------------------------------------------------------------------
__global__ __launch_bounds__(256, 2) void gemm_split(const float* __restrict__ A,
                                                     const uint4* __restrict__ Bp,
                                                     float* __restrict__ part) {
  const int S  = gridDim.y;
  const int mt = blockIdx.x, s = blockIdx.y;
  const int t  = threadIdx.x;
  const int w  = t >> 6, l = t & 63;
  const int wr = w >> 1, wc = w & 1;
  const int lm = l & 15, lq = l >> 4;
  const int row0 = mt * 128 + wr * 64;
  const int nt0  = wc * 10;
  const int kb0  = (int)((long long)KB_STEPS * s / S);
  const int kb1  = (int)((long long)KB_STEPS * (s + 1) / S);

  f32x4 acc[4][10];
#pragma unroll
  for (int i = 0; i < 4; ++i)
#pragma unroll
    for (int n = 0; n < 10; ++n) acc[i][n] = (f32x4)0.f;

  const float* ap[4];
#pragma unroll
  for (int i = 0; i < 4; ++i)
    ap[i] = A + (size_t)(row0 + i * 16 + lm) * F_SZ + (size_t)kb0 * 32 + lq * 8;
  const uint4* bp = Bp + ((size_t)kb0 * 20 + nt0) * 64 + l;

  for (int kb = kb0; kb < kb1; ++kb) {
    bf16x8 afrag[4];
    uint4 bv[10];
    if (kb != KB_STEPS - 1) {
      // --- stage bands 0,1 (16 raw regs), issue B loads, pack, stage 2,3 ---
      f4u r00 = *(const f4u*)(ap[0]);
      f4u r01 = *(const f4u*)(ap[0] + 4);
      f4u r10 = *(const f4u*)(ap[1]);
      f4u r11 = *(const f4u*)(ap[1] + 4);
#pragma unroll
      for (int n = 0; n < 10; ++n) bv[n] = bp[n * 64];
      {
        uint4 p0 = make_uint4(pack_bf16(r00[0], r00[1]), pack_bf16(r00[2], r00[3]),
                              pack_bf16(r01[0], r01[1]), pack_bf16(r01[2], r01[3]));
        afrag[0] = __builtin_bit_cast(bf16x8, p0);
        uint4 p1 = make_uint4(pack_bf16(r10[0], r10[1]), pack_bf16(r10[2], r10[3]),
                              pack_bf16(r11[0], r11[1]), pack_bf16(r11[2], r11[3]));
        afrag[1] = __builtin_bit_cast(bf16x8, p1);
      }
      {
        f4u r20 = *(const f4u*)(ap[2]);
        f4u r21 = *(const f4u*)(ap[2] + 4);
        f4u r30 = *(const f4u*)(ap[3]);
        f4u r31 = *(const f4u*)(ap[3] + 4);
        uint4 p2 = make_uint4(pack_bf16(r20[0], r20[1]), pack_bf16(r20[2], r20[3]),
                              pack_bf16(r21[0], r21[1]), pack_bf16(r21[2], r21[3]));
        afrag[2] = __builtin_bit_cast(bf16x8, p2);
        uint4 p3 = make_uint4(pack_bf16(r30[0], r30[1]), pack_bf16(r30[2], r30[3]),
                              pack_bf16(r31[0], r31[1]), pack_bf16(r31[2], r31[3]));
        afrag[3] = __builtin_bit_cast(bf16x8, p3);
      }
    } else {  // guarded tail: k >= F reads masked to 0 (Bp already zero there)
#pragma unroll
      for (int n = 0; n < 10; ++n) bv[n] = bp[n * 64];
      int kbase = kb * 32 + lq * 8;
#pragma unroll
      for (int i = 0; i < 4; ++i) {
        float f[8];
#pragma unroll
        for (int j = 0; j < 8; ++j) f[j] = (kbase + j < F_SZ) ? ap[i][j] : 0.f;
        uint4 pk = make_uint4(pack_bf16(f[0], f[1]), pack_bf16(f[2], f[3]),
                              pack_bf16(f[4], f[5]), pack_bf16(f[6], f[7]));
        afrag[i] = __builtin_bit_cast(bf16x8, pk);
      }
    }
    // n-outer MFMA loop: waits on bv[n] are staggered (fine-grained vmcnt)
#pragma unroll
    for (int n = 0; n < 10; ++n) {
      bf16x8 bf = __builtin_bit_cast(bf16x8, bv[n]);
#pragma unroll
      for (int i = 0; i < 4; ++i)
        acc[i][n] = __builtin_amdgcn_mfma_f32_16x16x32_bf16(afrag[i], bf,
                                                            acc[i][n], 0, 0, 0);
    }
#pragma unroll
    for (int i = 0; i < 4; ++i) ap[i] += 32;
    bp += 20 * 64;
  }

  // epilogue: C/D layout col = lane&15, row = (lane>>4)*4 + reg  [m89/m91]
  float* out = part + (size_t)s * PART_ELEMS;
#pragma unroll
  for (int i = 0; i < 4; ++i) {
    int rb = row0 + i * 16 + lq * 4;
#pragma unroll
    for (int n = 0; n < 10; ++n) {
      int col = (nt0 + n) * 16 + lm;
#pragma unroll
      for (int r = 0; r < 4; ++r)
        out[(size_t)(rb + r) * N_PAD + col] = acc[i][n][r];
    }
  }
}

// ---------------------------------------------------------------------------
// Kernel 3: per-row reduction of S partial slabs + FM epilogue.
// out[b] = w0 + C[b][312] + 0.5*(sum_k (sum_f C[b][8f+k])^2 - sum_{n<312} C^2)
// ---------------------------------------------------------------------------
__global__ __launch_bounds__(256) void finalize(const float* __restrict__ part,
                                                const float* __restrict__ w0,
                                                float* __restrict__ out, int S) {
  const int b = blockIdx.x;
  const int t = threadIdx.x;
  __shared__ float crow[N_PAD];
  __shared__ float red[4];
  __shared__ float skl[8];

  for (int n = t; n < N_PAD; n += 256) {
    float acc = 0.f;
    for (int s = 0; s < S; ++s)
      acc += part[(size_t)s * PART_ELEMS + (size_t)b * N_PAD + n];
    crow[n] = acc;
  }
  __syncthreads();

  float sq = 0.f;
  for (int n = t; n < N_RAW; n += 256) sq += crow[n] * crow[n];
#pragma unroll
  for (int off = 32; off; off >>= 1) sq += __shfl_down(sq, off);
  if ((t & 63) == 0) red[t >> 6] = sq;
  if (t < 8) {
    float sk = 0.f;
#pragma unroll
    for (int f = 0; f < NFIELD; ++f) sk += crow[f * 8 + t];
    skl[t] = sk;
  }
  __syncthreads();
  if (t == 0) {
    float sumsq = red[0] + red[1] + red[2] + red[3];
    float ss = 0.f;
#pragma unroll
    for (int k = 0; k < 8; ++k) ss += skl[k] * skl[k];
    out[b] = w0[0] + crow[312] + 0.5f * (ss - sumsq);
  }
}

extern "C" void kernel_launch(void* const* d_in, const int* in_sizes, int n_in,
                              void* d_out, int out_size, void* d_ws, size_t ws_size,
                              hipStream_t stream) {
  const float* inputs = (const float*)d_in[0];
  const float* w0 = (const float*)d_in[1];
  const float* w  = (const float*)d_in[2];
  const float* v  = (const float*)d_in[3];
  float* out = (float*)d_out;

  const size_t PART_BYTES   = PART_ELEMS * sizeof(float);           // 1.31 MB
  const size_t PACKED_BYTES = (size_t)KB_STEPS * 20 * 64 * 16;      // 66.6 MB
  int S = 64;
  while (S > 1 && PACKED_BYTES + (size_t)S * PART_BYTES > ws_size) S >>= 1;

  float* part = (float*)d_ws;
  uint4* Bp   = (uint4*)((char*)d_ws + (size_t)S * PART_BYTES);

  pack_v<<<dim3(KB_STEPS), 256, 0, stream>>>(v, w, Bp);
  gemm_split<<<dim3(8, S), 256, 0, stream>>>(inputs, Bp, part);
  finalize<<<dim3(B_SZ), 256, 0, stream>>>(part, w0, out, S);
}

// Round 3
// 747.707 us; speedup vs baseline: 1.0658x; 1.0658x over previous
//
#include <hip/hip_runtime.h>
#include <stdint.h>

#define B_SZ 1024
#define F_SZ 104013
#define NFIELD 39
#define N_RAW 312
#define N_PAD 320
#define KB_STEPS 3251            // ceil(104013 / 32)
#define PART_ELEMS ((size_t)B_SZ * N_PAD)

using bf16x8 = __attribute__((ext_vector_type(8))) short;
using f32x4  = __attribute__((ext_vector_type(4))) float;

typedef __attribute__((address_space(3))) void* lds_vp;
typedef const __attribute__((address_space(1))) void* glb_cvp;

__device__ __forceinline__ void ld16(const void* g, void* l) {
  // async global->LDS DMA, 16B per lane; LDS dest = uniform base + lane*16
  __builtin_amdgcn_global_load_lds((glb_cvp)g, (lds_vp)l, 16, 0, 0);
}

__device__ __forceinline__ unsigned int pack_bf16(float a, float b) {
  // round-half-up to bf16, pack two into one dword (lo = a, hi = b)
  unsigned int ua = __float_as_uint(a) + 0x8000u;
  unsigned int ub = __float_as_uint(b) + 0x8000u;
  return (ua >> 16) | (ub & 0xffff0000u);
}

// ---------------------------------------------------------------------------
// Kernel 1: transpose+convert v (plus w as column 312, zero pad to 320) into
// MFMA B-fragment order: chunk index (kb*20+nt)*64 + lane holds 8 bf16 with
// B[k = kb*32 + (lane>>4)*8 + j][n = nt*16 + (lane&15)], 16B per lane.
// Rows with k >= F_SZ are zero (protects GEMM tail).
// ---------------------------------------------------------------------------
__global__ __launch_bounds__(256) void pack_v(const float* __restrict__ v,
                                              const float* __restrict__ w,
                                              uint4* __restrict__ Bp) {
  const int kb = blockIdx.x;
  const int t  = threadIdx.x;
  __shared__ float vs[32][324];

  for (int idx = t; idx < 32 * 78; idx += 256) {
    int r = idx / 78, c4 = (idx % 78) * 4;
    int k = kb * 32 + r;
    float4 val = make_float4(0.f, 0.f, 0.f, 0.f);
    if (k < F_SZ) val = *(const float4*)(v + (size_t)k * N_RAW + c4);
    *(float4*)&vs[r][c4] = val;
  }
  if (t < 32) {
    int k = kb * 32 + t;
    vs[t][312] = (k < F_SZ) ? w[k] : 0.f;
#pragma unroll
    for (int c = 313; c < 320; ++c) vs[t][c] = 0.f;
  }
  __syncthreads();

#pragma unroll
  for (int i = 0; i < 5; ++i) {
    int p  = t + 256 * i;          // p = nt*64 + lane
    int l  = p & 63;
    int kr = (l >> 4) * 8;
    int col = (p >> 6) * 16 + (l & 15);
    uint4 o;
    o.x = pack_bf16(vs[kr + 0][col], vs[kr + 1][col]);
    o.y = pack_bf16(vs[kr + 2][col], vs[kr + 3][col]);
    o.z = pack_bf16(vs[kr + 4][col], vs[kr + 5][col]);
    o.w = pack_bf16(vs[kr + 6][col], vs[kr + 7][col]);
    Bp[(size_t)kb * 1280 + p] = o;
  }
}

// ---------------------------------------------------------------------------
// Kernel 2: split-K MFMA GEMM, m97-style async LDS double-buffer.
// Block: 4 waves, tile 128 rows x 320 cols; wave = 64 rows x 160 cols.
// Per kb: prefetch kb+1's A (16KB) + B (20KB) via global_load_lds into the
// other buffer while computing kb from LDS. A source addresses carry a
// per-row k-rotation so LDS fragment reads are 2-way-conflict-only.
// LDS 72KB -> 2 blocks/CU; VGPR ~236 -> 2 waves/SIMD.
// ---------------------------------------------------------------------------
__global__ __launch_bounds__(256, 2) void gemm_split(const float* __restrict__ A,
                                                     const uint4* __restrict__ Bp,
                                                     float* __restrict__ part) {
  const int S  = gridDim.y;
  const int mt = blockIdx.x, s = blockIdx.y;
  const int t  = threadIdx.x;
  const int w  = t >> 6, l = t & 63;
  const int wr = w >> 1, wc = w & 1;
  const int lm = l & 15, lq = l >> 4;
  const int row0 = mt * 128;
  const int kb0 = (int)((long long)KB_STEPS * s / S);
  const int kb1 = (int)((long long)KB_STEPS * (s + 1) / S);

  __shared__ __align__(16) char smem[2][36864];  // per buf: A 16K | B 20K

  // A staging geometry: inst g (wave w owns g = w*4..w*4+3), lane l loads
  // A[row0 + g*8 + (l>>3)][kb*32 + kgl*4 .. +4) -> smem + g*1024 + l*16
  // kgl = ((l&7) - (l>>3)) & 7  : row-rotated k-group
  const int lr  = l >> 3;
  const int kgl = ((l & 7) - lr) & 7;
  size_t arowbase[4];
#pragma unroll
  for (int j = 0; j < 4; ++j)
    arowbase[j] = (size_t)(row0 + (w * 4 + j) * 8 + lr) * F_SZ + (size_t)(kgl * 4);

  auto stage = [&](int kb, int buf, bool withA) {
    if (withA) {
#pragma unroll
      for (int j = 0; j < 4; ++j)
        ld16(A + arowbase[j] + (size_t)kb * 32, smem[buf] + (w * 4 + j) * 1024);
    }
#pragma unroll
    for (int j = 0; j < 5; ++j)
      ld16(Bp + ((size_t)kb * 20 + w * 5 + j) * 64 + l,
           smem[buf] + 16384 + (w * 5 + j) * 1024);
  };

  f32x4 acc[4][10];
#pragma unroll
  for (int i = 0; i < 4; ++i)
#pragma unroll
    for (int n = 0; n < 10; ++n) acc[i][n] = (f32x4)0.f;

  stage(kb0, 0, true);   // kb0 <= 3200 < tail, always safe
  int cur = 0;
  for (int kb = kb0; kb < kb1; ++kb) {
    __syncthreads();     // implicit vmcnt(0): buf[cur] fully staged, all waves
    if (kb + 1 < kb1) stage(kb + 1, cur ^ 1, (kb + 1) != KB_STEPS - 1);

    bf16x8 afrag[4];
    if (kb != KB_STEPS - 1) {
      const char* base = smem[cur];
      const int rot = lm & 7;
      const int p0 = (lq * 2 + rot) & 7;
      const int p1 = (lq * 2 + 1 + rot) & 7;
#pragma unroll
      for (int i = 0; i < 4; ++i) {
        int rowq = wr * 8 + i * 2 + (lm >> 3);
        f32x4 r0 = *(const f32x4*)(base + rowq * 1024 + rot * 128 + p0 * 16);
        f32x4 r1 = *(const f32x4*)(base + rowq * 1024 + rot * 128 + p1 * 16);
        uint4 pk = make_uint4(pack_bf16(r0[0], r0[1]), pack_bf16(r0[2], r0[3]),
                              pack_bf16(r1[0], r1[1]), pack_bf16(r1[2], r1[3]));
        afrag[i] = __builtin_bit_cast(bf16x8, pk);
      }
    } else {  // tail kb: guarded direct-global (k=104012 straddles a 16B group)
      int kbase = kb * 32 + lq * 8;
#pragma unroll
      for (int i = 0; i < 4; ++i) {
        const float* ap = A + (size_t)(row0 + wr * 64 + i * 16 + lm) * F_SZ;
        float f[8];
#pragma unroll
        for (int jj = 0; jj < 8; ++jj)
          f[jj] = (kbase + jj < F_SZ) ? ap[kbase + jj] : 0.f;
        uint4 pk = make_uint4(pack_bf16(f[0], f[1]), pack_bf16(f[2], f[3]),
                              pack_bf16(f[4], f[5]), pack_bf16(f[6], f[7]));
        afrag[i] = __builtin_bit_cast(bf16x8, pk);
      }
    }

#pragma unroll
    for (int n = 0; n < 10; ++n) {
      bf16x8 bf = __builtin_bit_cast(
          bf16x8, *(const uint4*)(smem[cur] + 16384 + (wc * 10 + n) * 1024 + l * 16));
#pragma unroll
      for (int i = 0; i < 4; ++i)
        acc[i][n] = __builtin_amdgcn_mfma_f32_16x16x32_bf16(afrag[i], bf,
                                                            acc[i][n], 0, 0, 0);
    }
    cur ^= 1;
  }

  // epilogue: C/D layout col = lane&15, row = (lane>>4)*4 + reg
  float* out = part + (size_t)s * PART_ELEMS;
#pragma unroll
  for (int i = 0; i < 4; ++i) {
    int rb = row0 + wr * 64 + i * 16 + lq * 4;
#pragma unroll
    for (int n = 0; n < 10; ++n) {
      int col = (wc * 10 + n) * 16 + lm;
#pragma unroll
      for (int r = 0; r < 4; ++r)
        out[(size_t)(rb + r) * N_PAD + col] = acc[i][n][r];
    }
  }
}

// ---------------------------------------------------------------------------
// Kernel 3: per-row reduction of S partial slabs + FM epilogue.
// out[b] = w0 + C[b][312] + 0.5*(sum_k (sum_f C[b][8f+k])^2 - sum_{n<312} C^2)
// ---------------------------------------------------------------------------
__global__ __launch_bounds__(256) void finalize(const float* __restrict__ part,
                                                const float* __restrict__ w0,
                                                float* __restrict__ out, int S) {
  const int b = blockIdx.x;
  const int t = threadIdx.x;
  __shared__ float crow[N_PAD];
  __shared__ float red[4];
  __shared__ float skl[8];

  for (int n = t; n < N_PAD; n += 256) {
    float acc = 0.f;
    for (int s = 0; s < S; ++s)
      acc += part[(size_t)s * PART_ELEMS + (size_t)b * N_PAD + n];
    crow[n] = acc;
  }
  __syncthreads();

  float sq = 0.f;
  for (int n = t; n < N_RAW; n += 256) sq += crow[n] * crow[n];
#pragma unroll
  for (int off = 32; off; off >>= 1) sq += __shfl_down(sq, off);
  if ((t & 63) == 0) red[t >> 6] = sq;
  if (t < 8) {
    float sk = 0.f;
#pragma unroll
    for (int f = 0; f < NFIELD; ++f) sk += crow[f * 8 + t];
    skl[t] = sk;
  }
  __syncthreads();
  if (t == 0) {
    float sumsq = red[0] + red[1] + red[2] + red[3];
    float ss = 0.f;
#pragma unroll
    for (int k = 0; k < 8; ++k) ss += skl[k] * skl[k];
    out[b] = w0[0] + crow[312] + 0.5f * (ss - sumsq);
  }
}

extern "C" void kernel_launch(void* const* d_in, const int* in_sizes, int n_in,
                              void* d_out, int out_size, void* d_ws, size_t ws_size,
                              hipStream_t stream) {
  const float* inputs = (const float*)d_in[0];
  const float* w0 = (const float*)d_in[1];
  const float* w  = (const float*)d_in[2];
  const float* v  = (const float*)d_in[3];
  float* out = (float*)d_out;

  const size_t PART_BYTES   = PART_ELEMS * sizeof(float);           // 1.31 MB
  const size_t PACKED_BYTES = (size_t)KB_STEPS * 20 * 64 * 16;      // 66.6 MB
  int S = 64;
  while (S > 1 && PACKED_BYTES + (size_t)S * PART_BYTES > ws_size) S >>= 1;

  float* part = (float*)d_ws;
  uint4* Bp   = (uint4*)((char*)d_ws + (size_t)S * PART_BYTES);

  pack_v<<<dim3(KB_STEPS), 256, 0, stream>>>(v, w, Bp);
  gemm_split<<<dim3(8, S), 256, 0, stream>>>(inputs, Bp, part);
  finalize<<<dim3(B_SZ), 256, 0, stream>>>(part, w0, out, S);
}